// Round 1
// baseline (62.559 us; speedup 1.0000x reference)
//
#include <hip/hip_runtime.h>
#include <hip/hip_bf16.h>

// out[t,f,d] = sum_{c=0..9} table[x[t,f,c], d] * w[c],  w[c] = (10-c)/55
// x: (1024,64,10) int32 in [0,8000); table: (8000,256) f32; out: (1024,64,256) f32
//
// One 64-lane wave per output row. Lane i handles float4 at d = 4*i.
// Table-row reads and output writes are 1 KB contiguous per wave (coalesced).
// Index loads are wave-uniform (broadcast). Table (8 MB) lives in L2/L3, so
// HBM traffic ~= 64 MB write + ~10 MB read  ->  memory(write)-bound.

#define ROWS_TOTAL (1024 * 64)   // 65536 rows of 256 floats
#define WAVES_PER_BLOCK 4

__global__ __launch_bounds__(64 * WAVES_PER_BLOCK)
void char2vec_kernel(const int* __restrict__ x,
                     const float* __restrict__ table,
                     float* __restrict__ out) {
    const int wave = threadIdx.x >> 6;
    const int lane = threadIdx.x & 63;
    const int row  = blockIdx.x * WAVES_PER_BLOCK + wave;
    if (row >= ROWS_TOTAL) return;

    const int* __restrict__ xi = x + row * 10;

    // Prefetch all 10 wave-uniform indices first (ILP: 10 loads in flight).
    int idx[10];
#pragma unroll
    for (int c = 0; c < 10; ++c) idx[c] = xi[c];

    // Normalized weights (10-c)/55, compile-time constants.
    const float w0 = 10.0f / 55.0f, w1 = 9.0f / 55.0f, w2 = 8.0f / 55.0f,
                w3 = 7.0f / 55.0f,  w4 = 6.0f / 55.0f, w5 = 5.0f / 55.0f,
                w6 = 4.0f / 55.0f,  w7 = 3.0f / 55.0f, w8 = 2.0f / 55.0f,
                w9 = 1.0f / 55.0f;
    const float w[10] = {w0, w1, w2, w3, w4, w5, w6, w7, w8, w9};

    const int doff = lane * 4;  // float4 slot within the 256-wide row

    // Issue all 10 table loads, then FMA. Compiler will software-pipeline.
    float4 v[10];
#pragma unroll
    for (int c = 0; c < 10; ++c) {
        v[c] = *reinterpret_cast<const float4*>(table + (size_t)idx[c] * 256 + doff);
    }

    float4 acc = make_float4(0.f, 0.f, 0.f, 0.f);
#pragma unroll
    for (int c = 0; c < 10; ++c) {
        acc.x = fmaf(w[c], v[c].x, acc.x);
        acc.y = fmaf(w[c], v[c].y, acc.y);
        acc.z = fmaf(w[c], v[c].z, acc.z);
        acc.w = fmaf(w[c], v[c].w, acc.w);
    }

    *reinterpret_cast<float4*>(out + (size_t)row * 256 + doff) = acc;
}

extern "C" void kernel_launch(void* const* d_in, const int* in_sizes, int n_in,
                              void* d_out, int out_size, void* d_ws, size_t ws_size,
                              hipStream_t stream) {
    const int*   x     = (const int*)d_in[0];
    const float* table = (const float*)d_in[1];
    float*       out   = (float*)d_out;

    const int blocks = ROWS_TOTAL / WAVES_PER_BLOCK;  // 16384
    char2vec_kernel<<<blocks, 64 * WAVES_PER_BLOCK, 0, stream>>>(x, table, out);
}

// Round 2
// 32.793 us; speedup vs baseline: 1.9077x; 1.9077x over previous
//
#include <hip/hip_runtime.h>
#include <hip/hip_bf16.h>

// out[t,f,d] = sum_{c=0..9} table[x[t,f,c], d] * w[c],  w[c] = (10-c)/55
// x: (1024,64,10) int32; table: (8000,256) f32; out: (1024,64,256) f32
//
// R1: XCD-sliced d-partition. Block b owns d-slice (b & 7) of 32 floats
// (128 B). Consecutive blockIdx round-robin across the 8 XCDs, so each
// XCD's gather working set is 8000 rows x 128 B = 1 MB -> resident in its
// 4 MB L2. Table HBM fetch drops to ~8 MB total (no cross-XCD replication).
// 8-lane groups per row: gathers/stores are 128 B-aligned full lines.
// Nontemporal output stores keep the write stream from evicting the slice.

#define ROWS_TOTAL (1024 * 64)   // 65536 rows of 256 floats

typedef float v4f __attribute__((ext_vector_type(4)));

__global__ __launch_bounds__(256)
void char2vec_sliced(const int* __restrict__ x,
                     const float* __restrict__ table,
                     float* __restrict__ out) {
    const int slice = blockIdx.x & 7;        // -> XCD (round-robin heuristic)
    const int rgrp  = blockIdx.x >> 3;       // row-group of 32 rows
    const int wave  = threadIdx.x >> 6;
    const int lane  = threadIdx.x & 63;

    const int row = rgrp * 32 + wave * 8 + (lane >> 3);   // 8 rows per wave
    const int d   = slice * 32 + (lane & 7) * 4;          // float4 within slice

    // 10 indices for this row, loaded as 5x int2 (8B-aligned: row*40 % 8 == 0).
    // Uniform within each 8-lane group -> broadcast-friendly.
    const int2* __restrict__ xi2 = reinterpret_cast<const int2*>(x + row * 10);
    int idx[10];
#pragma unroll
    for (int i = 0; i < 5; ++i) {
        int2 p = xi2[i];
        idx[2 * i]     = p.x;
        idx[2 * i + 1] = p.y;
    }

    const float w[10] = {10.f / 55.f, 9.f / 55.f, 8.f / 55.f, 7.f / 55.f,
                         6.f / 55.f,  5.f / 55.f, 4.f / 55.f, 3.f / 55.f,
                         2.f / 55.f,  1.f / 55.f};

    // Issue all 10 gathers (independent, in flight together), then FMA.
    v4f v[10];
#pragma unroll
    for (int c = 0; c < 10; ++c) {
        v[c] = *reinterpret_cast<const v4f*>(table + (size_t)idx[c] * 256 + d);
    }

    v4f acc = (v4f)0.0f;
#pragma unroll
    for (int c = 0; c < 10; ++c) {
        acc += v[c] * w[c];
    }

    __builtin_nontemporal_store(
        acc, reinterpret_cast<v4f*>(out + (size_t)row * 256 + d));
}

extern "C" void kernel_launch(void* const* d_in, const int* in_sizes, int n_in,
                              void* d_out, int out_size, void* d_ws, size_t ws_size,
                              hipStream_t stream) {
    const int*   x     = (const int*)d_in[0];
    const float* table = (const float*)d_in[1];
    float*       out   = (float*)d_out;

    // 32 rows per block, 8 d-slices: 65536/32 * 8 = 16384 blocks.
    const int blocks = (ROWS_TOTAL / 32) * 8;
    char2vec_sliced<<<blocks, 256, 0, stream>>>(x, table, out);
}

// Round 3
// 31.945 us; speedup vs baseline: 1.9583x; 1.0265x over previous
//
#include <hip/hip_runtime.h>
#include <hip/hip_bf16.h>

// out[t,f,d] = sum_{c=0..9} table[x[t,f,c], d] * w[c],  w[c] = (10-c)/55
// x: (1024,64,10) int32; table: (8000,256) f32; out: (1024,64,256) f32
//
// R2: XCD-sliced d-partition (as R1: block b owns d-slice b&7, 128 B of each
// table row; per-XCD gather working set = 1 MB, L2-resident) PLUS 2 rows per
// thread to double memory-level parallelism. Each thread issues 10 int2 index
// loads + 20 float4 gathers before consuming -> ~2x outstanding L2 lines,
// closing the Little's-law gap (L2-hit latency ~250 cyc x needed ~260
// lines/CU).

#define ROWS_TOTAL (1024 * 64)   // 65536 rows of 256 floats

typedef float v4f __attribute__((ext_vector_type(4)));

__global__ __launch_bounds__(256)
void char2vec_sliced2(const int* __restrict__ x,
                      const float* __restrict__ table,
                      float* __restrict__ out) {
    const int slice = blockIdx.x & 7;        // -> XCD (round-robin)
    const int rgrp  = blockIdx.x >> 3;       // row-group of 64 rows
    const int wave  = threadIdx.x >> 6;
    const int lane  = threadIdx.x & 63;

    // Each 8-lane group handles 2 consecutive rows; 8 groups/wave, 4 waves.
    const int row0 = rgrp * 64 + wave * 16 + (lane >> 3) * 2;
    const int row1 = row0 + 1;
    const int d    = slice * 32 + (lane & 7) * 4;   // float4 within slice

    // 20 indices (2 rows x 10), via int2 (row*40 is always 8B-aligned).
    const int2* __restrict__ xa = reinterpret_cast<const int2*>(x + row0 * 10);
    const int2* __restrict__ xb = reinterpret_cast<const int2*>(x + row1 * 10);
    int2 pa[5], pb[5];
#pragma unroll
    for (int i = 0; i < 5; ++i) pa[i] = xa[i];
#pragma unroll
    for (int i = 0; i < 5; ++i) pb[i] = xb[i];

    int ia[10], ib[10];
#pragma unroll
    for (int i = 0; i < 5; ++i) {
        ia[2 * i] = pa[i].x; ia[2 * i + 1] = pa[i].y;
        ib[2 * i] = pb[i].x; ib[2 * i + 1] = pb[i].y;
    }

    // Issue all 20 gathers (independent, all in flight), then FMA.
    v4f va[10], vb[10];
#pragma unroll
    for (int c = 0; c < 10; ++c)
        va[c] = *reinterpret_cast<const v4f*>(table + (size_t)ia[c] * 256 + d);
#pragma unroll
    for (int c = 0; c < 10; ++c)
        vb[c] = *reinterpret_cast<const v4f*>(table + (size_t)ib[c] * 256 + d);

    const float w[10] = {10.f / 55.f, 9.f / 55.f, 8.f / 55.f, 7.f / 55.f,
                         6.f / 55.f,  5.f / 55.f, 4.f / 55.f, 3.f / 55.f,
                         2.f / 55.f,  1.f / 55.f};

    v4f acc0 = (v4f)0.0f, acc1 = (v4f)0.0f;
#pragma unroll
    for (int c = 0; c < 10; ++c) {
        acc0 += va[c] * w[c];
        acc1 += vb[c] * w[c];
    }

    __builtin_nontemporal_store(
        acc0, reinterpret_cast<v4f*>(out + (size_t)row0 * 256 + d));
    __builtin_nontemporal_store(
        acc1, reinterpret_cast<v4f*>(out + (size_t)row1 * 256 + d));
}

extern "C" void kernel_launch(void* const* d_in, const int* in_sizes, int n_in,
                              void* d_out, int out_size, void* d_ws, size_t ws_size,
                              hipStream_t stream) {
    const int*   x     = (const int*)d_in[0];
    const float* table = (const float*)d_in[1];
    float*       out   = (float*)d_out;

    // 64 rows per block, 8 d-slices: 65536/64 * 8 = 8192 blocks.
    const int blocks = (ROWS_TOTAL / 64) * 8;
    char2vec_sliced2<<<blocks, 256, 0, stream>>>(x, table, out);
}